// Round 9
// baseline (209.495 us; speedup 1.0000x reference)
//
#include <hip/hip_runtime.h>
#include <hip/hip_fp16.h>

#define C 128
#define NEG_SLOPE 0.2f
#define SM_EPS 1e-16f
#define BKT_SHIFT 8            // 256 nodes per bucket
#define BKT_MASK 255
#define BIN_CHUNK 8192
#define WP 136                 // LDS pitch (u16) for h-writeback slice

typedef unsigned int uint32;
typedef __attribute__((ext_vector_type(8))) short bf16x8;
typedef __attribute__((ext_vector_type(4))) float f32x4;

// ---- bf16 helpers (RNE) ----
static __device__ __forceinline__ unsigned short f2bf(float f) {
    uint32 u = __float_as_uint(f);
    uint32 r = 0x7FFFu + ((u >> 16) & 1u);
    return (unsigned short)((u + r) >> 16);
}
static __device__ __forceinline__ uint32 f2bf2(float lo, float hi) {
    return (uint32)f2bf(lo) | ((uint32)f2bf(hi) << 16);
}
// ---- f16 bit helpers ----
static __device__ __forceinline__ uint32 f2h(float f) {
    __half h = __float2half(f);
    return (uint32)*reinterpret_cast<unsigned short*>(&h);
}
static __device__ __forceinline__ float h2f(uint32 b) {
    unsigned short s = (unsigned short)(b & 0xffffu);
    __half h = *reinterpret_cast<__half*>(&s);
    return __half2float(h);
}

// ---- W -> bf16 fragment-ordered + zero bucket_cnt/progress ----
__global__ __launch_bounds__(256) void cvtw_kernel(const float* __restrict__ W,
                                                   uint32* __restrict__ Wf,
                                                   int* __restrict__ bucket_cnt,
                                                   int* __restrict__ bucket_progress, int NB) {
    int gid = blockIdx.x * 256 + threadIdx.x;       // 0..8191
    if (blockIdx.x == 0 && threadIdx.x < NB) {
        bucket_cnt[threadIdx.x] = 0;
        bucket_progress[threadIdx.x] = 0;
    }
    int j2   = gid & 3;
    int lane = (gid >> 2) & 63;
    int tile = gid >> 8;                            // t*4+kk
    int t = tile >> 2, kk = tile & 3;
    int n = t * 16 + (lane & 15);
    int k = kk * 32 + (lane >> 4) * 8 + j2 * 2;
    Wf[gid] = f2bf2(W[k * C + n], W[(k + 1) * C + n]);
}

// ---- MFMA GEMM + alpha reductions + bf16 h + fused bucket hist ----
__global__ __launch_bounds__(256) void gemm_hist_kernel(
    const float* __restrict__ x, const uint32* __restrict__ Wf,
    const float* __restrict__ a_src, const float* __restrict__ a_dst,
    unsigned short* __restrict__ hb, float* __restrict__ as_out,
    float* __restrict__ ad_out, int N,
    const int* __restrict__ dst, int* __restrict__ bucket_cnt, int E, int total, int NB)
{
    __shared__ __align__(16) unsigned short slice[4][16 * WP];
    __shared__ int bhist[256];

    const int tid  = threadIdx.x;
    const int lane = tid & 63;
    const int w    = tid >> 6;
    const int row0 = blockIdx.x * 64;
    const int m16  = lane & 15;
    const int q    = lane >> 4;

    bhist[tid] = 0;

    const int row = row0 + w * 16 + m16;
    const bool rv = (row < N);
    const float* xr_p = x + (size_t)(rv ? row : 0) * C + q * 8;

    float4 xr[8];
    #pragma unroll
    for (int kk = 0; kk < 4; ++kk) {
        xr[kk * 2]     = rv ? *(const float4*)(xr_p + kk * 32)     : make_float4(0, 0, 0, 0);
        xr[kk * 2 + 1] = rv ? *(const float4*)(xr_p + kk * 32 + 4) : make_float4(0, 0, 0, 0);
    }

    f32x4 acc[8];
    const f32x4 zz = {0.f, 0.f, 0.f, 0.f};
    #pragma unroll
    for (int t = 0; t < 8; ++t) acc[t] = zz;

    #pragma unroll
    for (int kk = 0; kk < 4; ++kk) {
        union { bf16x8 v; uint32 u[4]; } au;
        float4 p0 = xr[kk * 2], p1 = xr[kk * 2 + 1];
        au.u[0] = f2bf2(p0.x, p0.y); au.u[1] = f2bf2(p0.z, p0.w);
        au.u[2] = f2bf2(p1.x, p1.y); au.u[3] = f2bf2(p1.z, p1.w);
        #pragma unroll
        for (int t = 0; t < 8; ++t) {
            bf16x8 b = *(const bf16x8*)&Wf[((t * 4 + kk) * 64 + lane) * 4];
            acc[t] = __builtin_amdgcn_mfma_f32_16x16x32_bf16(au.v, b, acc[t], 0, 0, 0);
        }
    }

    float ps[4] = {0.f, 0.f, 0.f, 0.f}, pd[4] = {0.f, 0.f, 0.f, 0.f};
    #pragma unroll
    for (int t = 0; t < 8; ++t) {
        float av = a_src[t * 16 + m16];
        float dv = a_dst[t * 16 + m16];
        #pragma unroll
        for (int r = 0; r < 4; ++r) {
            ps[r] += acc[t][r] * av;
            pd[r] += acc[t][r] * dv;
        }
    }
    #pragma unroll
    for (int r = 0; r < 4; ++r) {
        #pragma unroll
        for (int off = 1; off < 16; off <<= 1) {
            ps[r] += __shfl_xor(ps[r], off, 64);
            pd[r] += __shfl_xor(pd[r], off, 64);
        }
    }
    if (m16 == 0) {
        #pragma unroll
        for (int r = 0; r < 4; ++r) {
            int rr = row0 + w * 16 + q * 4 + r;
            if (rr < N) { as_out[rr] = ps[r]; ad_out[rr] = pd[r]; }
        }
    }

    #pragma unroll
    for (int t = 0; t < 8; ++t)
        #pragma unroll
        for (int r = 0; r < 4; ++r)
            slice[w][(q * 4 + r) * WP + t * 16 + m16] = f2bf(acc[t][r]);
    __syncthreads();
    #pragma unroll
    for (int it = 0; it < 4; ++it) {
        int r = it * 4 + q;
        int rr = row0 + w * 16 + r;
        if (rr < N) {
            bf16x8 v = *(const bf16x8*)&slice[w][r * WP + m16 * 8];
            *(bf16x8*)&hb[(size_t)rr * C + m16 * 8] = v;
        }
    }

    for (int i = blockIdx.x * 256 + tid; i < total; i += gridDim.x * 256) {
        int d = (i < E) ? dst[i] : (i - E);
        atomicAdd(&bhist[d >> BKT_SHIFT], 1);
    }
    __syncthreads();
    if (tid < NB && bhist[tid]) atomicAdd(&bucket_cnt[tid], bhist[tid]);
}

// ---- bin: LDS-staged scatter; per-block redundant scan of bucket counts ----
__global__ __launch_bounds__(1024) void bin_kernel(
    const int* __restrict__ src, const int* __restrict__ dst,
    const int* __restrict__ bucket_cnt, int* __restrict__ bucket_progress,
    uint32* __restrict__ packed, int E, int total, int NB)
{
    __shared__ uint32 lsrc[BIN_CHUNK];           // 32 KB
    __shared__ unsigned short ldst[BIN_CHUNK];   // 16 KB
    __shared__ int hist[256];
    __shared__ int base[256];
    __shared__ int boff[256];
    __shared__ int wave_tot[4];
    const int tid = threadIdx.x;
    const int start = blockIdx.x * BIN_CHUNK;
    const int end = min(start + BIN_CHUNK, total);
    const int n = end - start;

    // redundant exclusive scan of bucket_cnt (NB <= 256)
    int v = 0, xx = 0;
    if (tid < 256) {
        hist[tid] = 0;
        const int lane = tid & 63;
        v = (tid < NB) ? bucket_cnt[tid] : 0;
        xx = v;
        #pragma unroll
        for (int o = 1; o < 64; o <<= 1) {
            int t = __shfl_up(xx, o, 64);
            if (lane >= o) xx += t;
        }
        if (lane == 63) wave_tot[tid >> 6] = xx;
    }
    // stage chunk
    for (int i = start + tid; i < end; i += 1024) {
        int s = (i < E) ? src[i] : (i - E);
        int d = (i < E) ? dst[i] : (i - E);
        lsrc[i - start] = (uint32)s;
        ldst[i - start] = (unsigned short)d;
    }
    __syncthreads();
    if (tid < 256) {
        const int wid = tid >> 6;
        int wbase = 0;
        #pragma unroll
        for (int w = 0; w < 4; ++w) wbase += (w < wid) ? wave_tot[w] : 0;
        boff[tid] = wbase + xx - v;
    }
    __syncthreads();
    for (int j = tid; j < n; j += 1024)
        atomicAdd(&hist[ldst[j] >> BKT_SHIFT], 1);
    __syncthreads();
    if (tid < NB) {
        int c = hist[tid];
        base[tid] = boff[tid] + (c ? atomicAdd(&bucket_progress[tid], c) : 0);
    }
    if (tid < 256) hist[tid] = 0;
    __syncthreads();
    for (int j = tid; j < n; j += 1024) {
        int d = ldst[j];
        int b = d >> BKT_SHIFT;
        int pos = base[b] + atomicAdd(&hist[b], 1);
        packed[pos] = (lsrc[j] << BKT_SHIFT) | (uint32)(d & BKT_MASK);
    }
}

// ---- build: per-bucket fine sort + fused e; per-block redundant scan ----
__global__ __launch_bounds__(1024) void build_kernel(
    const uint32* __restrict__ packed, const int* __restrict__ bucket_cnt,
    const float* __restrict__ as, const float* __restrict__ ad,
    int* __restrict__ row_start, uint32* __restrict__ csr, int N, int NB, int total)
{
    __shared__ int cnt[256];
    __shared__ int cur[256];
    __shared__ float adl[256];
    __shared__ int boff[256];
    __shared__ int wave_tot[8];
    const int tid = threadIdx.x;
    const int b = blockIdx.x;

    // redundant scan of bucket_cnt to get this bucket's offset
    int v = 0, xx = 0;
    if (tid < 256) {
        const int lane = tid & 63;
        v = (tid < NB) ? bucket_cnt[tid] : 0;
        xx = v;
        #pragma unroll
        for (int o = 1; o < 64; o <<= 1) {
            int t = __shfl_up(xx, o, 64);
            if (lane >= o) xx += t;
        }
        if (lane == 63) wave_tot[tid >> 6] = xx;
        cnt[tid] = 0;
        int g = (b << BKT_SHIFT) + tid;
        adl[tid] = (g < N) ? ad[g] : 0.f;
    }
    __syncthreads();
    if (tid < 256) {
        const int wid = tid >> 6;
        int wbase = 0;
        #pragma unroll
        for (int w = 0; w < 4; ++w) wbase += (w < wid) ? wave_tot[w] : 0;
        boff[tid] = wbase + xx - v;
    }
    __syncthreads();
    const int off = boff[b];
    const int end = off + ((b < NB) ? bucket_cnt[b] : 0);
    if (b == 0 && tid == 0) row_start[N] = total;

    for (int j = off + tid; j < end; j += 1024)
        atomicAdd(&cnt[packed[j] & BKT_MASK], 1);
    __syncthreads();

    int v2 = 0, x2 = 0;
    if (tid < 256) {
        const int lane = tid & 63;
        v2 = cnt[tid]; x2 = v2;
        #pragma unroll
        for (int o = 1; o < 64; o <<= 1) {
            int t = __shfl_up(x2, o, 64);
            if (lane >= o) x2 += t;
        }
        if (lane == 63) wave_tot[4 + (tid >> 6)] = x2;
    }
    __syncthreads();
    if (tid < 256) {
        const int wid = tid >> 6;
        int wbase = 0;
        #pragma unroll
        for (int w = 0; w < 4; ++w) wbase += (w < wid) ? wave_tot[4 + w] : 0;
        int excl = wbase + x2 - v2;
        int g = (b << BKT_SHIFT) + tid;
        if (g < N) row_start[g] = off + excl;
        cur[tid] = excl;
    }
    __syncthreads();

    for (int j = off + tid; j < end; j += 1024) {
        uint32 p = packed[j];
        int l = (int)(p & BKT_MASK);
        int s = (int)(p >> BKT_SHIFT);
        float e = as[s] + adl[l];
        e = (e > 0.f) ? e : NEG_SLOPE * e;
        int pos = atomicAdd(&cur[l], 1);
        csr[off + pos] = ((uint32)s << 16) | f2h(e);
    }
}

// ---- full-wave fallback for deg>64 nodes ----
static __device__ __forceinline__ void gather_node_fw(
    int d, const uint32* __restrict__ csr, const int* __restrict__ row_start,
    const unsigned short* __restrict__ hb, const float* __restrict__ bias,
    float* __restrict__ out, int lane)
{
    const int beg = row_start[d];
    const int deg = row_start[d + 1] - beg;
    const int c2 = lane << 1;
    float a0 = 0.f, a1 = 0.f;
    float m = -INFINITY;
    for (int t = lane; t < deg; t += 64) m = fmaxf(m, h2f(csr[beg + t]));
    #pragma unroll
    for (int off = 32; off > 0; off >>= 1) m = fmaxf(m, __shfl_xor(m, off, 64));
    float ssum = 0.f;
    for (int t = lane; t < deg; t += 64) ssum += __expf(h2f(csr[beg + t]) - m);
    #pragma unroll
    for (int off = 32; off > 0; off >>= 1) ssum += __shfl_xor(ssum, off, 64);
    float inv = 1.f / (ssum + SM_EPS);
    for (int t0 = 0; t0 < deg; t0 += 64) {
        int nc = min(64, deg - t0);
        uint32 ent = (lane < nc) ? csr[beg + t0 + lane] : 0xFC00u;
        float wl = (lane < nc) ? __expf(h2f(ent) - m) * inv : 0.f;
        uint32 bc = (ent & 0xffff0000u) | f2h(wl);
        for (int t = 0; t < nc; ++t) {
            uint32 b0 = (uint32)__shfl((int)bc, t, 64);
            uint32 u0 = *(const uint32*)&hb[(size_t)(b0 >> 16) * C + c2];
            float w0 = h2f(b0);
            a0 += __uint_as_float(u0 << 16) * w0;
            a1 += __uint_as_float(u0 & 0xffff0000u) * w0;
        }
    }
    float2 b2 = *(const float2*)&bias[c2];
    a0 = fmaxf(a0 + b2.x, 0.f);
    a1 = fmaxf(a1 + b2.y, 0.f);
    *(float2*)&out[(size_t)d * C + c2] = make_float2(a0, a1);
}

// ---- half-wave gather: 2 dst nodes per wave, 4 channels per lane ----
__global__ __launch_bounds__(256) void gather_kernel(
    const uint32* __restrict__ csr, const int* __restrict__ row_start,
    const unsigned short* __restrict__ hb, const float* __restrict__ bias,
    float* __restrict__ out, int N)
{
    const int w    = threadIdx.x >> 6;
    const int lane = threadIdx.x & 63;
    const int half = lane >> 5;
    const int hl   = lane & 31;
    const int pair = blockIdx.x * 4 + w;
    const int d0 = pair * 2;
    if (d0 >= N) return;                    // no barriers below: safe
    const int d = d0 + half;
    const bool valid = (d < N);

    int beg = 0, deg = 0;
    if (valid) { beg = row_start[d]; deg = row_start[d + 1] - beg; }

    int wdeg = deg;
    #pragma unroll
    for (int off = 32; off > 0; off >>= 1) wdeg = max(wdeg, __shfl_xor(wdeg, off, 64));

    if (wdeg > 64) {
        gather_node_fw(d0, csr, row_start, hb, bias, out, lane);
        if (d0 + 1 < N) gather_node_fw(d0 + 1, csr, row_start, hb, bias, out, lane);
        return;
    }

    uint32 ent0 = (hl < deg) ? csr[beg + hl] : 0xFC00u;
    uint32 ent1 = (32 + hl < deg) ? csr[beg + 32 + hl] : 0xFC00u;
    float e0 = h2f(ent0), e1 = h2f(ent1);
    float m = fmaxf(e0, e1);
    #pragma unroll
    for (int off = 16; off > 0; off >>= 1) m = fmaxf(m, __shfl_xor(m, off, 64));
    float p0 = (hl < deg) ? __expf(e0 - m) : 0.f;
    float p1 = (32 + hl < deg) ? __expf(e1 - m) : 0.f;
    float ssum = p0 + p1;
    #pragma unroll
    for (int off = 16; off > 0; off >>= 1) ssum += __shfl_xor(ssum, off, 64);
    const float inv = 1.f / (ssum + SM_EPS);
    // packed broadcast entries: src<<16 | f16(weight); invalid -> 0 (w=0)
    uint32 bc0 = (hl < deg) ? ((ent0 & 0xffff0000u) | f2h(p0 * inv)) : 0u;
    uint32 bc1 = (32 + hl < deg) ? ((ent1 & 0xffff0000u) | f2h(p1 * inv)) : 0u;

    const int c4 = hl << 2;
    const int hbase = half << 5;
    float a0 = 0.f, a1 = 0.f, a2 = 0.f, a3 = 0.f;

    const int n1 = min(wdeg, 32);
    int t = 0;
    for (; t + 2 <= n1; t += 2) {
        uint32 bA = (uint32)__shfl((int)bc0, hbase + t, 64);
        uint32 bB = (uint32)__shfl((int)bc0, hbase + t + 1, 64);
        uint2 uA = *(const uint2*)&hb[(size_t)(bA >> 16) * C + c4];
        uint2 uB = *(const uint2*)&hb[(size_t)(bB >> 16) * C + c4];
        float wA = h2f(bA), wB = h2f(bB);
        a0 += __uint_as_float(uA.x << 16) * wA + __uint_as_float(uB.x << 16) * wB;
        a1 += __uint_as_float(uA.x & 0xffff0000u) * wA + __uint_as_float(uB.x & 0xffff0000u) * wB;
        a2 += __uint_as_float(uA.y << 16) * wA + __uint_as_float(uB.y << 16) * wB;
        a3 += __uint_as_float(uA.y & 0xffff0000u) * wA + __uint_as_float(uB.y & 0xffff0000u) * wB;
    }
    for (; t < n1; ++t) {
        uint32 bA = (uint32)__shfl((int)bc0, hbase + t, 64);
        uint2 uA = *(const uint2*)&hb[(size_t)(bA >> 16) * C + c4];
        float wA = h2f(bA);
        a0 += __uint_as_float(uA.x << 16) * wA;
        a1 += __uint_as_float(uA.x & 0xffff0000u) * wA;
        a2 += __uint_as_float(uA.y << 16) * wA;
        a3 += __uint_as_float(uA.y & 0xffff0000u) * wA;
    }
    for (t = 32; t + 2 <= wdeg; t += 2) {
        uint32 bA = (uint32)__shfl((int)bc1, hbase + t - 32, 64);
        uint32 bB = (uint32)__shfl((int)bc1, hbase + t - 31, 64);
        uint2 uA = *(const uint2*)&hb[(size_t)(bA >> 16) * C + c4];
        uint2 uB = *(const uint2*)&hb[(size_t)(bB >> 16) * C + c4];
        float wA = h2f(bA), wB = h2f(bB);
        a0 += __uint_as_float(uA.x << 16) * wA + __uint_as_float(uB.x << 16) * wB;
        a1 += __uint_as_float(uA.x & 0xffff0000u) * wA + __uint_as_float(uB.x & 0xffff0000u) * wB;
        a2 += __uint_as_float(uA.y << 16) * wA + __uint_as_float(uB.y << 16) * wB;
        a3 += __uint_as_float(uA.y & 0xffff0000u) * wA + __uint_as_float(uB.y & 0xffff0000u) * wB;
    }
    for (; t < wdeg; ++t) {
        uint32 bA = (uint32)__shfl((int)bc1, hbase + t - 32, 64);
        uint2 uA = *(const uint2*)&hb[(size_t)(bA >> 16) * C + c4];
        float wA = h2f(bA);
        a0 += __uint_as_float(uA.x << 16) * wA;
        a1 += __uint_as_float(uA.x & 0xffff0000u) * wA;
        a2 += __uint_as_float(uA.y << 16) * wA;
        a3 += __uint_as_float(uA.y & 0xffff0000u) * wA;
    }

    if (valid) {
        float4 bb = *(const float4*)&bias[c4];
        float4 o;
        o.x = fmaxf(a0 + bb.x, 0.f);
        o.y = fmaxf(a1 + bb.y, 0.f);
        o.z = fmaxf(a2 + bb.z, 0.f);
        o.w = fmaxf(a3 + bb.w, 0.f);
        *(float4*)&out[(size_t)d * C + c4] = o;
    }
}

extern "C" void kernel_launch(void* const* d_in, const int* in_sizes, int n_in,
                              void* d_out, int out_size, void* d_ws, size_t ws_size,
                              hipStream_t stream) {
    const float* x     = (const float*)d_in[0];
    const float* W     = (const float*)d_in[1];
    const float* a_src = (const float*)d_in[2];
    const float* a_dst = (const float*)d_in[3];
    const float* bias  = (const float*)d_in[4];
    const int*   edge  = (const int*)d_in[5];

    const int N = in_sizes[0] / C;
    const int E = in_sizes[5] / 2;
    const int total = E + N;
    const int* src = edge;
    const int* dst = edge + E;
    float* out = (float*)d_out;

    const int NB = (N + BKT_MASK) >> BKT_SHIFT;   // 196 buckets

    // workspace (4B units):
    // hb[N*C/2] | as[N] | ad[N] | row_start[N+2] | packed[total] | csr[total]
    // | Wf[8192] | bucket_cnt[NB] | bucket_progress[NB]
    float* ws = (float*)d_ws;
    unsigned short* hb = (unsigned short*)ws;
    float* as = (float*)(hb + (size_t)N * C);
    float* ad = as + N;
    int* row_start       = (int*)(ad + N);
    uint32* packed       = (uint32*)(row_start + (N + 2));
    uint32* csr          = packed + total;
    uint32* Wf           = csr + total;
    int* bucket_cnt      = (int*)(Wf + 8192);
    int* bucket_progress = bucket_cnt + NB;

    cvtw_kernel<<<32, 256, 0, stream>>>(W, Wf, bucket_cnt, bucket_progress, NB);
    gemm_hist_kernel<<<(N + 63) / 64, 256, 0, stream>>>(
        x, Wf, a_src, a_dst, hb, as, ad, N, dst, bucket_cnt, E, total, NB);
    bin_kernel<<<(total + BIN_CHUNK - 1) / BIN_CHUNK, 1024, 0, stream>>>(
        src, dst, bucket_cnt, bucket_progress, packed, E, total, NB);
    build_kernel<<<NB, 1024, 0, stream>>>(packed, bucket_cnt, as, ad, row_start,
                                          csr, N, NB, total);
    gather_kernel<<<((N + 1) / 2 + 3) / 4, 256, 0, stream>>>(csr, row_start, hb, bias, out, N);
}

// Round 10
// 205.922 us; speedup vs baseline: 1.0174x; 1.0174x over previous
//
#include <hip/hip_runtime.h>
#include <hip/hip_fp16.h>

#define C 128
#define NEG_SLOPE 0.2f
#define SM_EPS 1e-16f
#define BKT_SHIFT 8            // 256 nodes per bucket
#define BKT_MASK 255
#define BIN_CHUNK 8192
#define WP 136                 // LDS pitch (u16) for h-writeback slice

typedef unsigned int uint32;
typedef __attribute__((ext_vector_type(8))) short bf16x8;
typedef __attribute__((ext_vector_type(4))) float f32x4;

// ---- bf16 helpers (RNE) ----
static __device__ __forceinline__ unsigned short f2bf(float f) {
    uint32 u = __float_as_uint(f);
    uint32 r = 0x7FFFu + ((u >> 16) & 1u);
    return (unsigned short)((u + r) >> 16);
}
static __device__ __forceinline__ uint32 f2bf2(float lo, float hi) {
    return (uint32)f2bf(lo) | ((uint32)f2bf(hi) << 16);
}
// ---- f16 bit helpers ----
static __device__ __forceinline__ uint32 f2h(float f) {
    __half h = __float2half(f);
    return (uint32)*reinterpret_cast<unsigned short*>(&h);
}
static __device__ __forceinline__ float h2f(uint32 b) {
    unsigned short s = (unsigned short)(b & 0xffffu);
    __half h = *reinterpret_cast<__half*>(&s);
    return __half2float(h);
}

// ---- W -> bf16 fragment-ordered + zero bucket_cnt/progress ----
__global__ __launch_bounds__(256) void cvtw_kernel(const float* __restrict__ W,
                                                   uint32* __restrict__ Wf,
                                                   int* __restrict__ bucket_cnt,
                                                   int* __restrict__ bucket_progress, int NB) {
    int gid = blockIdx.x * 256 + threadIdx.x;       // 0..8191
    if (blockIdx.x == 0 && threadIdx.x < NB) {
        bucket_cnt[threadIdx.x] = 0;
        bucket_progress[threadIdx.x] = 0;
    }
    int j2   = gid & 3;
    int lane = (gid >> 2) & 63;
    int tile = gid >> 8;                            // t*4+kk
    int t = tile >> 2, kk = tile & 3;
    int n = t * 16 + (lane & 15);
    int k = kk * 32 + (lane >> 4) * 8 + j2 * 2;
    Wf[gid] = f2bf2(W[k * C + n], W[(k + 1) * C + n]);
}

// ---- MFMA GEMM + alpha reductions + bf16 h + fused bucket hist ----
__global__ __launch_bounds__(256) void gemm_hist_kernel(
    const float* __restrict__ x, const uint32* __restrict__ Wf,
    const float* __restrict__ a_src, const float* __restrict__ a_dst,
    unsigned short* __restrict__ hb, float* __restrict__ as_out,
    float* __restrict__ ad_out, int N,
    const int* __restrict__ dst, int* __restrict__ bucket_cnt, int E, int total, int NB)
{
    __shared__ __align__(16) unsigned short slice[4][16 * WP];
    __shared__ int bhist[256];

    const int tid  = threadIdx.x;
    const int lane = tid & 63;
    const int w    = tid >> 6;
    const int row0 = blockIdx.x * 64;
    const int m16  = lane & 15;
    const int q    = lane >> 4;

    bhist[tid] = 0;

    const int row = row0 + w * 16 + m16;
    const bool rv = (row < N);
    const float* xr_p = x + (size_t)(rv ? row : 0) * C + q * 8;

    float4 xr[8];
    #pragma unroll
    for (int kk = 0; kk < 4; ++kk) {
        xr[kk * 2]     = rv ? *(const float4*)(xr_p + kk * 32)     : make_float4(0, 0, 0, 0);
        xr[kk * 2 + 1] = rv ? *(const float4*)(xr_p + kk * 32 + 4) : make_float4(0, 0, 0, 0);
    }

    f32x4 acc[8];
    const f32x4 zz = {0.f, 0.f, 0.f, 0.f};
    #pragma unroll
    for (int t = 0; t < 8; ++t) acc[t] = zz;

    #pragma unroll
    for (int kk = 0; kk < 4; ++kk) {
        union { bf16x8 v; uint32 u[4]; } au;
        float4 p0 = xr[kk * 2], p1 = xr[kk * 2 + 1];
        au.u[0] = f2bf2(p0.x, p0.y); au.u[1] = f2bf2(p0.z, p0.w);
        au.u[2] = f2bf2(p1.x, p1.y); au.u[3] = f2bf2(p1.z, p1.w);
        #pragma unroll
        for (int t = 0; t < 8; ++t) {
            bf16x8 b = *(const bf16x8*)&Wf[((t * 4 + kk) * 64 + lane) * 4];
            acc[t] = __builtin_amdgcn_mfma_f32_16x16x32_bf16(au.v, b, acc[t], 0, 0, 0);
        }
    }

    float ps[4] = {0.f, 0.f, 0.f, 0.f}, pd[4] = {0.f, 0.f, 0.f, 0.f};
    #pragma unroll
    for (int t = 0; t < 8; ++t) {
        float av = a_src[t * 16 + m16];
        float dv = a_dst[t * 16 + m16];
        #pragma unroll
        for (int r = 0; r < 4; ++r) {
            ps[r] += acc[t][r] * av;
            pd[r] += acc[t][r] * dv;
        }
    }
    #pragma unroll
    for (int r = 0; r < 4; ++r) {
        #pragma unroll
        for (int off = 1; off < 16; off <<= 1) {
            ps[r] += __shfl_xor(ps[r], off, 64);
            pd[r] += __shfl_xor(pd[r], off, 64);
        }
    }
    if (m16 == 0) {
        #pragma unroll
        for (int r = 0; r < 4; ++r) {
            int rr = row0 + w * 16 + q * 4 + r;
            if (rr < N) { as_out[rr] = ps[r]; ad_out[rr] = pd[r]; }
        }
    }

    #pragma unroll
    for (int t = 0; t < 8; ++t)
        #pragma unroll
        for (int r = 0; r < 4; ++r)
            slice[w][(q * 4 + r) * WP + t * 16 + m16] = f2bf(acc[t][r]);
    __syncthreads();
    #pragma unroll
    for (int it = 0; it < 4; ++it) {
        int r = it * 4 + q;
        int rr = row0 + w * 16 + r;
        if (rr < N) {
            bf16x8 v = *(const bf16x8*)&slice[w][r * WP + m16 * 8];
            *(bf16x8*)&hb[(size_t)rr * C + m16 * 8] = v;
        }
    }

    for (int i = blockIdx.x * 256 + tid; i < total; i += gridDim.x * 256) {
        int d = (i < E) ? dst[i] : (i - E);
        atomicAdd(&bhist[d >> BKT_SHIFT], 1);
    }
    __syncthreads();
    if (tid < NB && bhist[tid]) atomicAdd(&bucket_cnt[tid], bhist[tid]);
}

// ---- bin: LDS-staged scatter; per-block redundant scan of bucket counts ----
__global__ __launch_bounds__(1024) void bin_kernel(
    const int* __restrict__ src, const int* __restrict__ dst,
    const int* __restrict__ bucket_cnt, int* __restrict__ bucket_progress,
    uint32* __restrict__ packed, int E, int total, int NB)
{
    __shared__ uint32 lsrc[BIN_CHUNK];           // 32 KB
    __shared__ unsigned short ldst[BIN_CHUNK];   // 16 KB
    __shared__ int hist[256];
    __shared__ int base[256];
    __shared__ int boff[256];
    __shared__ int wave_tot[4];
    const int tid = threadIdx.x;
    const int start = blockIdx.x * BIN_CHUNK;
    const int end = min(start + BIN_CHUNK, total);
    const int n = end - start;

    // redundant exclusive scan of bucket_cnt (NB <= 256)
    int v = 0, xx = 0;
    if (tid < 256) {
        hist[tid] = 0;
        const int lane = tid & 63;
        v = (tid < NB) ? bucket_cnt[tid] : 0;
        xx = v;
        #pragma unroll
        for (int o = 1; o < 64; o <<= 1) {
            int t = __shfl_up(xx, o, 64);
            if (lane >= o) xx += t;
        }
        if (lane == 63) wave_tot[tid >> 6] = xx;
    }
    // stage chunk
    for (int i = start + tid; i < end; i += 1024) {
        int s = (i < E) ? src[i] : (i - E);
        int d = (i < E) ? dst[i] : (i - E);
        lsrc[i - start] = (uint32)s;
        ldst[i - start] = (unsigned short)d;
    }
    __syncthreads();
    if (tid < 256) {
        const int wid = tid >> 6;
        int wbase = 0;
        #pragma unroll
        for (int w = 0; w < 4; ++w) wbase += (w < wid) ? wave_tot[w] : 0;
        boff[tid] = wbase + xx - v;
    }
    __syncthreads();
    for (int j = tid; j < n; j += 1024)
        atomicAdd(&hist[ldst[j] >> BKT_SHIFT], 1);
    __syncthreads();
    if (tid < NB) {
        int c = hist[tid];
        base[tid] = boff[tid] + (c ? atomicAdd(&bucket_progress[tid], c) : 0);
    }
    if (tid < 256) hist[tid] = 0;
    __syncthreads();
    for (int j = tid; j < n; j += 1024) {
        int d = ldst[j];
        int b = d >> BKT_SHIFT;
        int pos = base[b] + atomicAdd(&hist[b], 1);
        packed[pos] = (lsrc[j] << BKT_SHIFT) | (uint32)(d & BKT_MASK);
    }
}

// ---- build: per-bucket fine sort + fused e; per-block redundant scan ----
__global__ __launch_bounds__(1024) void build_kernel(
    const uint32* __restrict__ packed, const int* __restrict__ bucket_cnt,
    const float* __restrict__ as, const float* __restrict__ ad,
    int* __restrict__ row_start, uint32* __restrict__ csr, int N, int NB, int total)
{
    __shared__ int cnt[256];
    __shared__ int cur[256];
    __shared__ float adl[256];
    __shared__ int boff[256];
    __shared__ int wave_tot[8];
    const int tid = threadIdx.x;
    const int b = blockIdx.x;

    int v = 0, xx = 0;
    if (tid < 256) {
        const int lane = tid & 63;
        v = (tid < NB) ? bucket_cnt[tid] : 0;
        xx = v;
        #pragma unroll
        for (int o = 1; o < 64; o <<= 1) {
            int t = __shfl_up(xx, o, 64);
            if (lane >= o) xx += t;
        }
        if (lane == 63) wave_tot[tid >> 6] = xx;
        cnt[tid] = 0;
        int g = (b << BKT_SHIFT) + tid;
        adl[tid] = (g < N) ? ad[g] : 0.f;
    }
    __syncthreads();
    if (tid < 256) {
        const int wid = tid >> 6;
        int wbase = 0;
        #pragma unroll
        for (int w = 0; w < 4; ++w) wbase += (w < wid) ? wave_tot[w] : 0;
        boff[tid] = wbase + xx - v;
    }
    __syncthreads();
    const int off = boff[b];
    const int end = off + ((b < NB) ? bucket_cnt[b] : 0);
    if (b == 0 && tid == 0) row_start[N] = total;

    for (int j = off + tid; j < end; j += 1024)
        atomicAdd(&cnt[packed[j] & BKT_MASK], 1);
    __syncthreads();

    int v2 = 0, x2 = 0;
    if (tid < 256) {
        const int lane = tid & 63;
        v2 = cnt[tid]; x2 = v2;
        #pragma unroll
        for (int o = 1; o < 64; o <<= 1) {
            int t = __shfl_up(x2, o, 64);
            if (lane >= o) x2 += t;
        }
        if (lane == 63) wave_tot[4 + (tid >> 6)] = x2;
    }
    __syncthreads();
    if (tid < 256) {
        const int wid = tid >> 6;
        int wbase = 0;
        #pragma unroll
        for (int w = 0; w < 4; ++w) wbase += (w < wid) ? wave_tot[4 + w] : 0;
        int excl = wbase + x2 - v2;
        int g = (b << BKT_SHIFT) + tid;
        if (g < N) row_start[g] = off + excl;
        cur[tid] = excl;
    }
    __syncthreads();

    for (int j = off + tid; j < end; j += 1024) {
        uint32 p = packed[j];
        int l = (int)(p & BKT_MASK);
        int s = (int)(p >> BKT_SHIFT);
        float e = as[s] + adl[l];
        e = (e > 0.f) ? e : NEG_SLOPE * e;
        int pos = atomicAdd(&cur[l], 1);
        csr[off + pos] = ((uint32)s << 16) | f2h(e);
    }
}

// ---- full-wave fallback for deg>64 nodes ----
static __device__ __forceinline__ void gather_node_fw(
    int d, const uint32* __restrict__ csr, const int* __restrict__ row_start,
    const unsigned short* __restrict__ hb, const float* __restrict__ bias,
    float* __restrict__ out, int lane)
{
    const int beg = row_start[d];
    const int deg = row_start[d + 1] - beg;
    const int c2 = lane << 1;
    float a0 = 0.f, a1 = 0.f;
    float m = -INFINITY;
    for (int t = lane; t < deg; t += 64) m = fmaxf(m, h2f(csr[beg + t]));
    #pragma unroll
    for (int off = 32; off > 0; off >>= 1) m = fmaxf(m, __shfl_xor(m, off, 64));
    float ssum = 0.f;
    for (int t = lane; t < deg; t += 64) ssum += __expf(h2f(csr[beg + t]) - m);
    #pragma unroll
    for (int off = 32; off > 0; off >>= 1) ssum += __shfl_xor(ssum, off, 64);
    float inv = 1.f / (ssum + SM_EPS);
    for (int t0 = 0; t0 < deg; t0 += 64) {
        int nc = min(64, deg - t0);
        uint32 ent = (lane < nc) ? csr[beg + t0 + lane] : 0xFC00u;
        float wl = (lane < nc) ? __expf(h2f(ent) - m) * inv : 0.f;
        uint32 bc = (ent & 0xffff0000u) | f2h(wl);
        for (int t = 0; t < nc; ++t) {
            uint32 b0 = (uint32)__shfl((int)bc, t, 64);
            uint32 u0 = *(const uint32*)&hb[(size_t)(b0 >> 16) * C + c2];
            float w0 = h2f(b0);
            a0 += __uint_as_float(u0 << 16) * w0;
            a1 += __uint_as_float(u0 & 0xffff0000u) * w0;
        }
    }
    float2 b2 = *(const float2*)&bias[c2];
    a0 = fmaxf(a0 + b2.x, 0.f);
    a1 = fmaxf(a1 + b2.y, 0.f);
    *(float2*)&out[(size_t)d * C + c2] = make_float2(a0, a1);
}

#define EDGE_FMA(bc_reg, idx)                                                     \
    {                                                                             \
        uint32 bE = (uint32)__shfl((int)(bc_reg), hbase + (idx), 64);             \
        uint2 uE = *(const uint2*)&hb[(size_t)(bE >> 16) * C + c4];               \
        float wE = h2f(bE);                                                       \
        a0 += __uint_as_float(uE.x << 16) * wE;                                   \
        a1 += __uint_as_float(uE.x & 0xffff0000u) * wE;                           \
        a2 += __uint_as_float(uE.y << 16) * wE;                                   \
        a3 += __uint_as_float(uE.y & 0xffff0000u) * wE;                           \
    }

// ---- half-wave gather: 2 dst nodes per wave, 4 ch/lane, unroll-8 ----
__global__ __launch_bounds__(256) void gather_kernel(
    const uint32* __restrict__ csr, const int* __restrict__ row_start,
    const unsigned short* __restrict__ hb, const float* __restrict__ bias,
    float* __restrict__ out, int N)
{
    const int w    = threadIdx.x >> 6;
    const int lane = threadIdx.x & 63;
    const int half = lane >> 5;
    const int hl   = lane & 31;
    const int pair = blockIdx.x * 4 + w;
    const int d0 = pair * 2;
    if (d0 >= N) return;                    // no barriers below: safe
    const int d = d0 + half;
    const bool valid = (d < N);

    int beg = 0, deg = 0;
    if (valid) { beg = row_start[d]; deg = row_start[d + 1] - beg; }

    int wdeg = deg;
    #pragma unroll
    for (int off = 32; off > 0; off >>= 1) wdeg = max(wdeg, __shfl_xor(wdeg, off, 64));

    if (wdeg > 64) {
        gather_node_fw(d0, csr, row_start, hb, bias, out, lane);
        if (d0 + 1 < N) gather_node_fw(d0 + 1, csr, row_start, hb, bias, out, lane);
        return;
    }

    uint32 ent0 = (hl < deg) ? csr[beg + hl] : 0xFC00u;
    uint32 ent1 = (32 + hl < deg) ? csr[beg + 32 + hl] : 0xFC00u;
    float e0 = h2f(ent0), e1 = h2f(ent1);
    float m = fmaxf(e0, e1);
    #pragma unroll
    for (int off = 16; off > 0; off >>= 1) m = fmaxf(m, __shfl_xor(m, off, 64));
    float p0 = (hl < deg) ? __expf(e0 - m) : 0.f;
    float p1 = (32 + hl < deg) ? __expf(e1 - m) : 0.f;
    float ssum = p0 + p1;
    #pragma unroll
    for (int off = 16; off > 0; off >>= 1) ssum += __shfl_xor(ssum, off, 64);
    const float inv = 1.f / (ssum + SM_EPS);
    // packed broadcast entries: src<<16 | f16(weight)
    uint32 bc0 = (hl < deg) ? ((ent0 & 0xffff0000u) | f2h(p0 * inv)) : 0u;
    uint32 bc1 = (32 + hl < deg) ? ((ent1 & 0xffff0000u) | f2h(p1 * inv)) : 0u;

    const int c4 = hl << 2;
    const int hbase = half << 5;
    float a0 = 0.f, a1 = 0.f, a2 = 0.f, a3 = 0.f;

    // each half loops to its OWN degree (divergence-masked; no wasted loads)
    const int n1 = min(deg, 32);
    int t = 0;
    for (; t + 8 <= n1; t += 8) {
        EDGE_FMA(bc0, t)     EDGE_FMA(bc0, t + 1) EDGE_FMA(bc0, t + 2) EDGE_FMA(bc0, t + 3)
        EDGE_FMA(bc0, t + 4) EDGE_FMA(bc0, t + 5) EDGE_FMA(bc0, t + 6) EDGE_FMA(bc0, t + 7)
    }
    for (; t < n1; ++t) { EDGE_FMA(bc0, t) }
    for (t = 32; t + 8 <= deg; t += 8) {
        EDGE_FMA(bc1, t - 32) EDGE_FMA(bc1, t - 31) EDGE_FMA(bc1, t - 30) EDGE_FMA(bc1, t - 29)
        EDGE_FMA(bc1, t - 28) EDGE_FMA(bc1, t - 27) EDGE_FMA(bc1, t - 26) EDGE_FMA(bc1, t - 25)
    }
    for (; t < deg; ++t) { EDGE_FMA(bc1, t - 32) }

    if (valid) {
        float4 bb = *(const float4*)&bias[c4];
        float4 o;
        o.x = fmaxf(a0 + bb.x, 0.f);
        o.y = fmaxf(a1 + bb.y, 0.f);
        o.z = fmaxf(a2 + bb.z, 0.f);
        o.w = fmaxf(a3 + bb.w, 0.f);
        *(float4*)&out[(size_t)d * C + c4] = o;
    }
}

extern "C" void kernel_launch(void* const* d_in, const int* in_sizes, int n_in,
                              void* d_out, int out_size, void* d_ws, size_t ws_size,
                              hipStream_t stream) {
    const float* x     = (const float*)d_in[0];
    const float* W     = (const float*)d_in[1];
    const float* a_src = (const float*)d_in[2];
    const float* a_dst = (const float*)d_in[3];
    const float* bias  = (const float*)d_in[4];
    const int*   edge  = (const int*)d_in[5];

    const int N = in_sizes[0] / C;
    const int E = in_sizes[5] / 2;
    const int total = E + N;
    const int* src = edge;
    const int* dst = edge + E;
    float* out = (float*)d_out;

    const int NB = (N + BKT_MASK) >> BKT_SHIFT;   // 196 buckets

    // workspace (4B units):
    // hb[N*C/2] | as[N] | ad[N] | row_start[N+2] | packed[total] | csr[total]
    // | Wf[8192] | bucket_cnt[NB] | bucket_progress[NB]
    float* ws = (float*)d_ws;
    unsigned short* hb = (unsigned short*)ws;
    float* as = (float*)(hb + (size_t)N * C);
    float* ad = as + N;
    int* row_start       = (int*)(ad + N);
    uint32* packed       = (uint32*)(row_start + (N + 2));
    uint32* csr          = packed + total;
    uint32* Wf           = csr + total;
    int* bucket_cnt      = (int*)(Wf + 8192);
    int* bucket_progress = bucket_cnt + NB;

    cvtw_kernel<<<32, 256, 0, stream>>>(W, Wf, bucket_cnt, bucket_progress, NB);
    gemm_hist_kernel<<<(N + 63) / 64, 256, 0, stream>>>(
        x, Wf, a_src, a_dst, hb, as, ad, N, dst, bucket_cnt, E, total, NB);
    bin_kernel<<<(total + BIN_CHUNK - 1) / BIN_CHUNK, 1024, 0, stream>>>(
        src, dst, bucket_cnt, bucket_progress, packed, E, total, NB);
    build_kernel<<<NB, 1024, 0, stream>>>(packed, bucket_cnt, as, ad, row_start,
                                          csr, N, NB, total);
    gather_kernel<<<((N + 1) / 2 + 3) / 4, 256, 0, stream>>>(csr, row_start, hb, bias, out, N);
}